// Round 8
// baseline (140.387 us; speedup 1.0000x reference)
//
#include <hip/hip_runtime.h>
#include <hip/hip_bf16.h>

#define NB 2
#define ND 256
#define NE 2048
#define NH 4
#define MAXP 8
#define PSTR8 2064   // LDS P row stride (bytes)

typedef __attribute__((ext_vector_type(8))) short bf16x8;
typedef __attribute__((ext_vector_type(4))) float f32x4;

static __device__ __forceinline__ short f2b(float f) {
    union { __hip_bfloat16 h; short s; } u;
    u.h = __float2bfloat16(f);
    return u.s;
}

static __device__ __forceinline__ float b2f(short s) {
    union { unsigned int u; float f; } u;
    u.u = ((unsigned int)(unsigned short)s) << 16;
    return u.f;
}

static __device__ __forceinline__ f32x4 mfma16(bf16x8 a, bf16x8 b, f32x4 c) {
    return __builtin_amdgcn_mfma_f32_16x16x32_bf16(a, b, c, 0, 0, 0);
}

static __device__ __forceinline__ f32x4 mfma8(long long a, long long b, f32x4 c) {
    return __builtin_amdgcn_mfma_f32_16x16x32_fp8_fp8(a, b, c, 0, 0, 0);
}

// ---------------- f32 -> bf16 convert, all 4 weight matrices ----------------
__global__ __launch_bounds__(256) void k_cvt_all(const float* __restrict__ w0,
        const float* __restrict__ w1, const float* __restrict__ w2,
        const float* __restrict__ w3, short* __restrict__ o0,
        short* __restrict__ o1, short* __restrict__ o2, short* __restrict__ o3) {
    int which = blockIdx.x >> 6;
    int i = (blockIdx.x & 63) * 256 + threadIdx.x;
    const float* in = which == 0 ? w0 : which == 1 ? w1 : which == 2 ? w2 : w3;
    short* out = which == 0 ? o0 : which == 1 ? o1 : which == 2 ? o2 : o3;
    float scale = which == 0 ? 0.125f : 1.0f;
    f32x4 v = ((const f32x4*)in)[i];
    short4 o;
    o.x = f2b(v[0] * scale); o.y = f2b(v[1] * scale);
    o.z = f2b(v[2] * scale); o.w = f2b(v[3] * scale);
    ((short4*)out)[i] = o;
}

// ---------------- fused transpose + layernorm: x [B,D,E] -> sbf, qnb ----------
// grid (NE/32, NB), block 256. Per block: 32 e-rows, all 256 d.
__global__ __launch_bounds__(256) void k_prep(const float* __restrict__ x,
        const float* __restrict__ g, const float* __restrict__ bb,
        short* __restrict__ sbf, short* __restrict__ qnb) {
    __shared__ float tileT[32][257];
    int b = blockIdx.y;
    int e0 = blockIdx.x * 32;
    int t = threadIdx.x;
    int tx = t & 31, ty = t >> 5; // 32 x 8
    #pragma unroll
    for (int d0 = 0; d0 < 256; d0 += 32) {
        #pragma unroll
        for (int r = 0; r < 4; r++) {
            int dd = d0 + ty + r * 8;
            tileT[tx][dd] = x[((size_t)b * ND + dd) * NE + e0 + tx];
        }
    }
    __syncthreads();
    int wave = t >> 6, lane = t & 63;
    #pragma unroll 1
    for (int rr = 0; rr < 8; rr++) {
        int e = wave * 8 + rr;
        float v0 = tileT[e][lane], v1 = tileT[e][lane + 64];
        float v2 = tileT[e][lane + 128], v3 = tileT[e][lane + 192];
        float sum = (v0 + v1) + (v2 + v3);
        #pragma unroll
        for (int off = 32; off; off >>= 1) sum += __shfl_xor(sum, off);
        float mean = sum * (1.0f / ND);
        float d0 = v0 - mean, d1 = v1 - mean, d2 = v2 - mean, d3 = v3 - mean;
        float sq = (d0 * d0 + d1 * d1) + (d2 * d2 + d3 * d3);
        #pragma unroll
        for (int off = 32; off; off >>= 1) sq += __shfl_xor(sq, off);
        float inv = rsqrtf(sq * (1.0f / ND) + 1e-6f);
        size_t base = ((size_t)b * NE + e0 + e) * ND;
        sbf[base + lane]       = f2b(v0);
        sbf[base + lane + 64]  = f2b(v1);
        sbf[base + lane + 128] = f2b(v2);
        sbf[base + lane + 192] = f2b(v3);
        qnb[base + lane]       = f2b(d0 * inv * g[lane]       + bb[lane]);
        qnb[base + lane + 64]  = f2b(d1 * inv * g[lane + 64]  + bb[lane + 64]);
        qnb[base + lane + 128] = f2b(d2 * inv * g[lane + 128] + bb[lane + 128]);
        qnb[base + lane + 192] = f2b(d3 * inv * g[lane + 192] + bb[lane + 192]);
    }
}

// ---------------- merged QKV MFMA GEMM (+ qdr table in z=0 epilogue) ----------
// grid (64, 4, 3): z=0 q->qbf + qdrT; z=1 k->kbf; z=2 v->vtb8 fp8 transposed
__global__ __launch_bounds__(256) void k_gemm_qkv(const short* __restrict__ qnb,
        const short* __restrict__ sbf, const short* __restrict__ wq,
        const short* __restrict__ wk, const short* __restrict__ wv,
        const float* __restrict__ w_rpr, short* __restrict__ qbf,
        short* __restrict__ kbf, unsigned char* __restrict__ vtb8,
        float* __restrict__ qdrT) {
    int z = blockIdx.z;
    const short* A = z == 0 ? qnb : sbf;
    const short* W = z == 0 ? wq : z == 1 ? wk : wv;
    int t = threadIdx.x;
    int wv_ = t >> 6, lane = t & 63;
    int l16 = lane & 15, g = lane >> 4, lk = g * 8;
    int m0 = blockIdx.x * 64, n0 = blockIdx.y * 64;
    int mw = m0 + wv_ * 16;
    const short* Ab = A + (size_t)(mw + l16) * 256 + lk;
    const short* Wb = W + (size_t)(n0 + l16) * 256 + lk;
    __shared__ float wr[9][64];
    if (z == 0) {
        for (int i = t; i < 576; i += 256) wr[i >> 6][i & 63] = w_rpr[i];
    }
    f32x4 acc[4];
    f32x4 z4 = {0.f, 0.f, 0.f, 0.f};
    #pragma unroll
    for (int c = 0; c < 4; c++) acc[c] = z4;
    #pragma unroll
    for (int kk = 0; kk < 8; kk++) {
        bf16x8 av = *(const bf16x8*)(Ab + kk * 32);
        #pragma unroll
        for (int c = 0; c < 4; c++) {
            bf16x8 bv = *(const bf16x8*)(Wb + (size_t)c * 16 * 256 + kk * 32);
            acc[c] = mfma16(av, bv, acc[c]);
        }
    }
    if (z < 2) {
        short* out = z == 0 ? qbf : kbf;
        #pragma unroll
        for (int c = 0; c < 4; c++)
            #pragma unroll
            for (int r = 0; r < 4; r++)
                out[(size_t)(mw + g * 4 + r) * 256 + n0 + c * 16 + l16] = f2b(acc[c][r]);
        if (z == 0) {
            __syncthreads();
            int h = blockIdx.y;
            #pragma unroll
            for (int r = 0; r < 4; r++) {
                size_t row = mw + g * 4 + r;
                size_t base = (row * NH + h) * 10;
                #pragma unroll
                for (int p = 0; p < 9; p++) {
                    float v = acc[0][r] * wr[p][l16] + acc[1][r] * wr[p][16 + l16]
                            + acc[2][r] * wr[p][32 + l16] + acc[3][r] * wr[p][48 + l16];
                    v += __shfl_xor(v, 1); v += __shfl_xor(v, 2);
                    v += __shfl_xor(v, 4); v += __shfl_xor(v, 8);
                    if (l16 == 0) qdrT[base + p] = __expf(v);
                }
                if (l16 == 0) qdrT[base + 9] = 0.f;
            }
        }
    } else {
        __shared__ unsigned char vt[64][72];
        #pragma unroll
        for (int c = 0; c < 4; c++) {
            #pragma unroll
            for (int r = 0; r < 4; r++) {
                unsigned u = __builtin_amdgcn_cvt_pk_fp8_f32(acc[c][r], 0.f, 0, false);
                vt[c * 16 + l16][wv_ * 16 + g * 4 + r] = (unsigned char)(u & 0xFF);
            }
        }
        __syncthreads();
        int b = m0 >> 11, e0 = m0 & (NE - 1);
        int bh = b * NH + blockIdx.y;
        int dl = t >> 2, ec = (t & 3) * 16;
        long long v0 = *(const long long*)&vt[dl][ec];
        long long v1 = *(const long long*)&vt[dl][ec + 8];
        size_t base = ((size_t)bh * 64 + dl) * NE + e0 + ec;
        *(long long*)&vtb8[base] = v0;
        *(long long*)&vtb8[base + 8] = v1;
    }
}

// ---------------- kernel A: scores -> exp -> fp8 P (into a_out rows) + rsums --
// grid (NE/16, NB*NH), block 512 (8 waves). Wave ph owns tiles n0=(ph+8j)*64.
// P fp8 stored in first 2048 bytes of each 8192-byte a_out row (same strip ->
// no cross-block aliasing; kernel B re-reads then overwrites with final f32).
__global__ __launch_bounds__(512, 4) void k_scores(
        const short* __restrict__ qbf, const short* __restrict__ kbf,
        const int* __restrict__ dist, const float* __restrict__ qdrT,
        unsigned char* __restrict__ a8, float* __restrict__ rsums) {
    __shared__ float qdr_lds[16][10];
    __shared__ float comb[8][16];
    int t = threadIdx.x;
    int ph = t >> 6, lane = t & 63;
    int l16 = lane & 15, g = lane >> 4, lk = g * 8;
    int bh = blockIdx.y, b = bh >> 2, h = bh & 3;
    int m0 = blockIdx.x * 16;

    if (t < 160) {
        int row = t / 10, p = t - row * 10;
        qdr_lds[row][p] = qdrT[((size_t)(b * NE + m0 + row) * NH + h) * 10 + p];
    }
    __syncthreads();

    const short* Abase = qbf + (size_t)(b * NE + m0 + l16) * 256 + h * 64 + lk;
    bf16x8 aq0 = *(const bf16x8*)(Abase);
    bf16x8 aq1 = *(const bf16x8*)(Abase + 32);

    const short* Kb = kbf + (size_t)(b * NE + l16) * 256 + h * 64 + lk;
    const int* distq = dist + ((size_t)(b * NE + m0 + l16)) * NE;
    unsigned char* Prow = a8 + ((size_t)(bh * NE + m0 + l16)) * (NE * 4);

    float rs = 0.f;

    #pragma unroll 2
    for (int j = 0; j < 4; j++) {
        int n0 = (ph + 8 * j) * 64;
        bf16x8 kv0[4], kv1[4];
        int4 dd4[4];
        #pragma unroll
        for (int c = 0; c < 4; c++) {
            const short* Bb = Kb + (size_t)(n0 + c * 16) * 256;
            kv0[c] = *(const bf16x8*)(Bb);
            kv1[c] = *(const bf16x8*)(Bb + 32);
            dd4[c] = *(const int4*)&distq[n0 + c * 16 + g * 4];
        }
        #pragma unroll
        for (int c = 0; c < 4; c++) {
            f32x4 acc = {0.f, 0.f, 0.f, 0.f};
            acc = mfma16(kv0[c], aq0, acc);
            acc = mfma16(kv1[c], aq1, acc);
            int kbase = n0 + c * 16 + g * 4;
            int4 dd = dd4[c];
            float e0 = __expf(acc[0]) * qdr_lds[l16][dd.x < 9 ? dd.x : 9];
            float e1 = __expf(acc[1]) * qdr_lds[l16][dd.y < 9 ? dd.y : 9];
            float e2 = __expf(acc[2]) * qdr_lds[l16][dd.z < 9 ? dd.z : 9];
            float e3 = __expf(acc[3]) * qdr_lds[l16][dd.w < 9 ? dd.w : 9];
            rs += (e0 + e1) + (e2 + e3);
            unsigned u = __builtin_amdgcn_cvt_pk_fp8_f32(e0, e1, 0, false);
            u = (unsigned)__builtin_amdgcn_cvt_pk_fp8_f32(e2, e3, (int)u, true);
            *(unsigned*)&Prow[kbase] = u;
        }
    }
    rs += __shfl_xor(rs, 16);
    rs += __shfl_xor(rs, 32);
    if (lane < 16) comb[ph][l16] = rs;
    __syncthreads();
    if (t < 16) {
        float s = 0.f;
        #pragma unroll
        for (int w = 0; w < 8; w++) s += comb[w][t];
        rsums[(size_t)bh * NE + m0 + t] = s;
    }
}

// ---------------- kernel B: stage P -> LDS; fp8 PV; normalized a_out; oatb ----
// grid (NE/16, NB*NH), block 512 (8 waves).
__global__ __launch_bounds__(512, 8) void k_pv(
        const unsigned char* __restrict__ vtb8, const float* __restrict__ rsums,
        float* __restrict__ a_out, short* __restrict__ oatb) {
    __shared__ __align__(16) unsigned char Pl[16][PSTR8];  // 33.0 KB
    __shared__ float inv_lds[16];
    int t = threadIdx.x;
    int ph = t >> 6, lane = t & 63;
    int l16 = lane & 15, g = lane >> 4;
    int bh = blockIdx.y, b = bh >> 2, h = bh & 3;
    int m0 = blockIdx.x * 16;
    const unsigned char* a8 = (const unsigned char*)a_out;

    // stage 16 rows x 2048B of fp8 P from global (a_out rows) into LDS
    {
        int r = t >> 5;            // 0..15
        int off = (t & 31) * 64;   // 0..1984
        const f32x4* src = (const f32x4*)(a8 + ((size_t)(bh * NE + m0 + r)) * (NE * 4) + off);
        f32x4 v0 = src[0], v1 = src[1], v2 = src[2], v3 = src[3];
        *(f32x4*)&Pl[r][off]      = v0;
        *(f32x4*)&Pl[r][off + 16] = v1;
        *(f32x4*)&Pl[r][off + 32] = v2;
        *(f32x4*)&Pl[r][off + 48] = v3;
    }
    if (t < 16) inv_lds[t] = 1.0f / rsums[(size_t)bh * NE + m0 + t];
    __syncthreads();

    const unsigned char* Vb0 = vtb8 + ((size_t)bh * 64 + l16) * NE;
    f32x4 accp[4];
    {
        f32x4 z4 = {0.f, 0.f, 0.f, 0.f};
        #pragma unroll
        for (int c = 0; c < 4; c++) accp[c] = z4;
    }
    #pragma unroll 1
    for (int j = 0; j < 4; j++) {
        int n0 = (ph + 8 * j) * 64;
        long long pa0 = *(const long long*)&Pl[l16][n0 + g * 8];
        long long pa1 = *(const long long*)&Pl[l16][n0 + 32 + g * 8];
        #pragma unroll
        for (int c = 0; c < 4; c++) {
            const unsigned char* Vb = Vb0 + (size_t)c * 16 * NE + n0 + g * 8;
            long long vb0 = *(const long long*)(Vb);
            long long vb1 = *(const long long*)(Vb + 32);
            accp[c] = mfma8(pa0, vb0, accp[c]);
            accp[c] = mfma8(pa1, vb1, accp[c]);
        }
        #pragma unroll
        for (int r4 = 0; r4 < 4; r4++) {
            int row = r4 * 4 + g;
            unsigned u = *(const unsigned*)&Pl[row][n0 + l16 * 4];
            float iv = inv_lds[row];
            f32x4 o;
            o[0] = __builtin_amdgcn_cvt_f32_fp8((int)u, 0) * iv;
            o[1] = __builtin_amdgcn_cvt_f32_fp8((int)u, 1) * iv;
            o[2] = __builtin_amdgcn_cvt_f32_fp8((int)u, 2) * iv;
            o[3] = __builtin_amdgcn_cvt_f32_fp8((int)u, 3) * iv;
            *(f32x4*)&a_out[((size_t)bh * NE + m0 + row) * NE + n0 + l16 * 4] = o;
        }
    }

    __syncthreads();
    float (*pvcomb)[16][64] = (float (*)[16][64])&Pl[0][0];  // 28.7 KB <= 33 KB
    if (ph > 0) {
        #pragma unroll
        for (int c = 0; c < 4; c++)
            #pragma unroll
            for (int r = 0; r < 4; r++)
                pvcomb[ph - 1][g * 4 + r][c * 16 + l16] = accp[c][r];
    }
    __syncthreads();
    if (ph == 0) {
        #pragma unroll
        for (int c = 0; c < 4; c++) {
            #pragma unroll
            for (int r = 0; r < 4; r++) {
                float v = accp[c][r];
                #pragma unroll
                for (int w = 0; w < 7; w++) v += pvcomb[w][g * 4 + r][c * 16 + l16];
                v *= inv_lds[g * 4 + r];
                oatb[(size_t)(b * NE + m0 + g * 4 + r) * 256 + h * 64 + c * 16 + l16] = f2b(v);
            }
        }
    }
}

// ---------------- fc GEMM + residual from x + transposed store ----------------
__global__ __launch_bounds__(256) void k_gemm_fc(const short* __restrict__ A,
        const short* __restrict__ W, const float* __restrict__ x,
        float* __restrict__ xout) {
    int t = threadIdx.x;
    int wv_ = t >> 6, lane = t & 63;
    int l16 = lane & 15, g = lane >> 4, lk = g * 8;
    int m0 = blockIdx.x * 64, n0 = blockIdx.y * 64;
    int mw = m0 + wv_ * 16;
    const short* Ab = A + (size_t)(mw + l16) * 256 + lk;
    const short* Wb = W + (size_t)(n0 + l16) * 256 + lk;
    f32x4 acc[4];
    f32x4 z4 = {0.f, 0.f, 0.f, 0.f};
    #pragma unroll
    for (int c = 0; c < 4; c++) acc[c] = z4;
    #pragma unroll
    for (int kk = 0; kk < 8; kk++) {
        bf16x8 av = *(const bf16x8*)(Ab + kk * 32);
        #pragma unroll
        for (int c = 0; c < 4; c++) {
            bf16x8 bv = *(const bf16x8*)(Wb + (size_t)c * 16 * 256 + kk * 32);
            acc[c] = mfma16(av, bv, acc[c]);
        }
    }
    __shared__ float tl[64][68];
    #pragma unroll
    for (int c = 0; c < 4; c++)
        #pragma unroll
        for (int r = 0; r < 4; r++)
            tl[c * 16 + l16][wv_ * 16 + g * 4 + r] = acc[c][r];
    __syncthreads();
    int b = m0 >> 11, e0 = m0 & (NE - 1);
    int dl = t >> 2, ec = (t & 3) * 16;
    #pragma unroll
    for (int i = 0; i < 4; i++) {
        size_t idx = ((size_t)b * ND + n0 + dl) * NE + e0 + ec + i * 4;
        f32x4 xv = *(const f32x4*)&x[idx];
        f32x4 v = *(f32x4*)&tl[dl][ec + i * 4];
        v[0] += xv[0]; v[1] += xv[1]; v[2] += xv[2]; v[3] += xv[3];
        *(f32x4*)&xout[idx] = v;
    }
}

extern "C" void kernel_launch(void* const* d_in, const int* in_sizes, int n_in,
                              void* d_out, int out_size, void* d_ws, size_t ws_size,
                              hipStream_t stream) {
    const float* x    = (const float*)d_in[0];
    const int*   dist = (const int*)d_in[1];
    const float* w_qs = (const float*)d_in[2];
    const float* w_ks = (const float*)d_in[3];
    const float* w_vs = (const float*)d_in[4];
    const float* w_fc = (const float*)d_in[5];
    const float* w_rpr= (const float*)d_in[6];
    const float* ln_g = (const float*)d_in[7];
    const float* ln_b = (const float*)d_in[8];

    char* ws = (char*)d_ws;
    short* sbf  = (short*)(ws);                    // 2 MB
    short* qnb  = (short*)(ws + (2u  << 20));      // 2 MB
    short* qbf  = (short*)(ws + (4u  << 20));      // 2 MB
    short* kbf  = (short*)(ws + (6u  << 20));      // 2 MB
    unsigned char* vtb8 = (unsigned char*)(ws + (8u << 20));  // 1 MB
    short* oatb = (short*)(ws + (10u << 20));      // 2 MB
    float* qdrT = (float*)(ws + (12u << 20));      // 640 KB
    short* wqsb = (short*)(ws + (13u << 20));
    short* wksb = (short*)(ws + (13u << 20) + 131072);
    short* wvsb = (short*)(ws + (13u << 20) + 262144);
    short* wfcb = (short*)(ws + (13u << 20) + 393216);
    float* rsums= (float*)(ws + (13u << 20) + 524288);  // 64 KB

    float* xout  = (float*)d_out;
    float* a_out = xout + (size_t)NB * ND * NE;

    k_cvt_all<<<dim3(256), dim3(256), 0, stream>>>(w_qs, w_ks, w_vs, w_fc,
                                                   wqsb, wksb, wvsb, wfcb);
    k_prep<<<dim3(NE / 32, NB), dim3(256), 0, stream>>>(x, ln_g, ln_b, sbf, qnb);
    k_gemm_qkv<<<dim3(64, 4, 3), dim3(256), 0, stream>>>(qnb, sbf, wqsb, wksb, wvsb,
                                                         w_rpr, qbf, kbf, vtb8, qdrT);
    k_scores<<<dim3(NE / 16, NB * NH), dim3(512), 0, stream>>>(qbf, kbf, dist, qdrT,
                                                               (unsigned char*)a_out, rsums);
    k_pv<<<dim3(NE / 16, NB * NH), dim3(512), 0, stream>>>(vtb8, rsums, a_out, oatb);
    k_gemm_fc<<<dim3(64, 4), dim3(256), 0, stream>>>(oatb, wfcb, x, xout);
}

// Round 9
// 126.583 us; speedup vs baseline: 1.1091x; 1.1091x over previous
//
#include <hip/hip_runtime.h>
#include <hip/hip_bf16.h>

#define NB 2
#define ND 256
#define NE 2048
#define NH 4
#define MAXP 8
#define PSTR8 2064   // LDS P row stride (bytes)

typedef __attribute__((ext_vector_type(8))) short bf16x8;
typedef __attribute__((ext_vector_type(4))) float f32x4;

static __device__ __forceinline__ short f2b(float f) {
    union { __hip_bfloat16 h; short s; } u;
    u.h = __float2bfloat16(f);
    return u.s;
}

static __device__ __forceinline__ float b2f(short s) {
    union { unsigned int u; float f; } u;
    u.u = ((unsigned int)(unsigned short)s) << 16;
    return u.f;
}

static __device__ __forceinline__ f32x4 mfma16(bf16x8 a, bf16x8 b, f32x4 c) {
    return __builtin_amdgcn_mfma_f32_16x16x32_bf16(a, b, c, 0, 0, 0);
}

static __device__ __forceinline__ f32x4 mfma8(long long a, long long b, f32x4 c) {
    return __builtin_amdgcn_mfma_f32_16x16x32_fp8_fp8(a, b, c, 0, 0, 0);
}

// ---------------- f32 -> bf16 convert, all 4 weight matrices ----------------
__global__ __launch_bounds__(256) void k_cvt_all(const float* __restrict__ w0,
        const float* __restrict__ w1, const float* __restrict__ w2,
        const float* __restrict__ w3, short* __restrict__ o0,
        short* __restrict__ o1, short* __restrict__ o2, short* __restrict__ o3) {
    int which = blockIdx.x >> 6;
    int i = (blockIdx.x & 63) * 256 + threadIdx.x;
    const float* in = which == 0 ? w0 : which == 1 ? w1 : which == 2 ? w2 : w3;
    short* out = which == 0 ? o0 : which == 1 ? o1 : which == 2 ? o2 : o3;
    float scale = which == 0 ? 0.125f : 1.0f;
    f32x4 v = ((const f32x4*)in)[i];
    short4 o;
    o.x = f2b(v[0] * scale); o.y = f2b(v[1] * scale);
    o.z = f2b(v[2] * scale); o.w = f2b(v[3] * scale);
    ((short4*)out)[i] = o;
}

// ---------------- fused transpose + layernorm: x [B,D,E] -> sbf, qnb ----------
__global__ __launch_bounds__(256) void k_prep(const float* __restrict__ x,
        const float* __restrict__ g, const float* __restrict__ bb,
        short* __restrict__ sbf, short* __restrict__ qnb) {
    __shared__ float tileT[32][257];
    int b = blockIdx.y;
    int e0 = blockIdx.x * 32;
    int t = threadIdx.x;
    int tx = t & 31, ty = t >> 5; // 32 x 8
    #pragma unroll
    for (int d0 = 0; d0 < 256; d0 += 32) {
        #pragma unroll
        for (int r = 0; r < 4; r++) {
            int dd = d0 + ty + r * 8;
            tileT[tx][dd] = x[((size_t)b * ND + dd) * NE + e0 + tx];
        }
    }
    __syncthreads();
    int wave = t >> 6, lane = t & 63;
    #pragma unroll 1
    for (int rr = 0; rr < 8; rr++) {
        int e = wave * 8 + rr;
        float v0 = tileT[e][lane], v1 = tileT[e][lane + 64];
        float v2 = tileT[e][lane + 128], v3 = tileT[e][lane + 192];
        float sum = (v0 + v1) + (v2 + v3);
        #pragma unroll
        for (int off = 32; off; off >>= 1) sum += __shfl_xor(sum, off);
        float mean = sum * (1.0f / ND);
        float d0 = v0 - mean, d1 = v1 - mean, d2 = v2 - mean, d3 = v3 - mean;
        float sq = (d0 * d0 + d1 * d1) + (d2 * d2 + d3 * d3);
        #pragma unroll
        for (int off = 32; off; off >>= 1) sq += __shfl_xor(sq, off);
        float inv = rsqrtf(sq * (1.0f / ND) + 1e-6f);
        size_t base = ((size_t)b * NE + e0 + e) * ND;
        sbf[base + lane]       = f2b(v0);
        sbf[base + lane + 64]  = f2b(v1);
        sbf[base + lane + 128] = f2b(v2);
        sbf[base + lane + 192] = f2b(v3);
        qnb[base + lane]       = f2b(d0 * inv * g[lane]       + bb[lane]);
        qnb[base + lane + 64]  = f2b(d1 * inv * g[lane + 64]  + bb[lane + 64]);
        qnb[base + lane + 128] = f2b(d2 * inv * g[lane + 128] + bb[lane + 128]);
        qnb[base + lane + 192] = f2b(d3 * inv * g[lane + 192] + bb[lane + 192]);
    }
}

// ---------------- merged QKV MFMA GEMM (+ qdr table in z=0 epilogue) ----------
__global__ __launch_bounds__(256) void k_gemm_qkv(const short* __restrict__ qnb,
        const short* __restrict__ sbf, const short* __restrict__ wq,
        const short* __restrict__ wk, const short* __restrict__ wv,
        const float* __restrict__ w_rpr, short* __restrict__ qbf,
        short* __restrict__ kbf, unsigned char* __restrict__ vtb8,
        float* __restrict__ qdrT) {
    int z = blockIdx.z;
    const short* A = z == 0 ? qnb : sbf;
    const short* W = z == 0 ? wq : z == 1 ? wk : wv;
    int t = threadIdx.x;
    int wv_ = t >> 6, lane = t & 63;
    int l16 = lane & 15, g = lane >> 4, lk = g * 8;
    int m0 = blockIdx.x * 64, n0 = blockIdx.y * 64;
    int mw = m0 + wv_ * 16;
    const short* Ab = A + (size_t)(mw + l16) * 256 + lk;
    const short* Wb = W + (size_t)(n0 + l16) * 256 + lk;
    __shared__ float wr[9][64];
    if (z == 0) {
        for (int i = t; i < 576; i += 256) wr[i >> 6][i & 63] = w_rpr[i];
    }
    f32x4 acc[4];
    f32x4 z4 = {0.f, 0.f, 0.f, 0.f};
    #pragma unroll
    for (int c = 0; c < 4; c++) acc[c] = z4;
    #pragma unroll
    for (int kk = 0; kk < 8; kk++) {
        bf16x8 av = *(const bf16x8*)(Ab + kk * 32);
        #pragma unroll
        for (int c = 0; c < 4; c++) {
            bf16x8 bv = *(const bf16x8*)(Wb + (size_t)c * 16 * 256 + kk * 32);
            acc[c] = mfma16(av, bv, acc[c]);
        }
    }
    if (z < 2) {
        short* out = z == 0 ? qbf : kbf;
        #pragma unroll
        for (int c = 0; c < 4; c++)
            #pragma unroll
            for (int r = 0; r < 4; r++)
                out[(size_t)(mw + g * 4 + r) * 256 + n0 + c * 16 + l16] = f2b(acc[c][r]);
        if (z == 0) {
            __syncthreads();
            int h = blockIdx.y;
            #pragma unroll
            for (int r = 0; r < 4; r++) {
                size_t row = mw + g * 4 + r;
                size_t base = (row * NH + h) * 10;
                #pragma unroll
                for (int p = 0; p < 9; p++) {
                    float v = acc[0][r] * wr[p][l16] + acc[1][r] * wr[p][16 + l16]
                            + acc[2][r] * wr[p][32 + l16] + acc[3][r] * wr[p][48 + l16];
                    v += __shfl_xor(v, 1); v += __shfl_xor(v, 2);
                    v += __shfl_xor(v, 4); v += __shfl_xor(v, 8);
                    if (l16 == 0) qdrT[base + p] = __expf(v);
                }
                if (l16 == 0) qdrT[base + 9] = 0.f;
            }
        }
    } else {
        __shared__ unsigned char vt[64][72];
        #pragma unroll
        for (int c = 0; c < 4; c++) {
            #pragma unroll
            for (int r = 0; r < 4; r++) {
                unsigned u = __builtin_amdgcn_cvt_pk_fp8_f32(acc[c][r], 0.f, 0, false);
                vt[c * 16 + l16][wv_ * 16 + g * 4 + r] = (unsigned char)(u & 0xFF);
            }
        }
        __syncthreads();
        int b = m0 >> 11, e0 = m0 & (NE - 1);
        int bh = b * NH + blockIdx.y;
        int dl = t >> 2, ec = (t & 3) * 16;
        long long v0 = *(const long long*)&vt[dl][ec];
        long long v1 = *(const long long*)&vt[dl][ec + 8];
        size_t base = ((size_t)bh * 64 + dl) * NE + e0 + ec;
        *(long long*)&vtb8[base] = v0;
        *(long long*)&vtb8[base + 8] = v1;
    }
}

// ---------------- fused scores+softmax+PV; fp8 P in LDS; high-ILP ------------
// grid (NE/16, NB*NH), block 512 (8 waves), launch_bounds (512,4): VGPR<=128.
// Wave ph owns tiles n0=(ph+8j)*64. Swapped mfma(K,Q); e=exp(s)*T[min(dd,9)].
// Pass 1 groups 12 K-loads + 4 dist int4 loads per j and prefetches next-j
// dist; pass 2 groups the 8 V loads per j.
__global__ __launch_bounds__(512, 4) void k_attn(
        const short* __restrict__ qbf, const short* __restrict__ kbf,
        const int* __restrict__ dist, const float* __restrict__ qdrT,
        const unsigned char* __restrict__ vtb8, float* __restrict__ a_out,
        short* __restrict__ oatb) {
    __shared__ __align__(16) unsigned char P[16][PSTR8];  // 33.0 KB fp8
    __shared__ float qdr_lds[16][10];
    __shared__ float comb[8][16];
    __shared__ float inv_lds[16];

    int t = threadIdx.x;
    int ph = t >> 6, lane = t & 63;
    int l16 = lane & 15, g = lane >> 4, lk = g * 8;
    int bh = blockIdx.y, b = bh >> 2, h = bh & 3;
    int m0 = blockIdx.x * 16;

    if (t < 160) {
        int row = t / 10, p = t - row * 10;
        qdr_lds[row][p] = qdrT[((size_t)(b * NE + m0 + row) * NH + h) * 10 + p];
    }
    __syncthreads();

    const short* Abase = qbf + (size_t)(b * NE + m0 + l16) * 256 + h * 64 + lk;
    bf16x8 aq0 = *(const bf16x8*)(Abase);
    bf16x8 aq1 = *(const bf16x8*)(Abase + 32);

    const short* Kb = kbf + (size_t)(b * NE + l16) * 256 + h * 64 + lk;
    const int* distq = dist + ((size_t)(b * NE + m0 + l16)) * NE;

    float rs = 0.f;

    // ---------------- pass 1: scores -> exp -> fp8 P, row sums ----------------
    int4 dd4[4], ddn[4];
    #pragma unroll
    for (int c = 0; c < 4; c++)
        dd4[c] = *(const int4*)&distq[ph * 64 + c * 16 + g * 4];
    #pragma unroll 1
    for (int j = 0; j < 4; j++) {
        int n0 = (ph + 8 * j) * 64;
        bf16x8 kv0[4], kv1[4];
        #pragma unroll
        for (int c = 0; c < 4; c++) {
            const short* Bb = Kb + (size_t)(n0 + c * 16) * 256;
            kv0[c] = *(const bf16x8*)(Bb);
            kv1[c] = *(const bf16x8*)(Bb + 32);
        }
        if (j < 3) {
            #pragma unroll
            for (int c = 0; c < 4; c++)
                ddn[c] = *(const int4*)&distq[n0 + 512 + c * 16 + g * 4];
        }
        #pragma unroll
        for (int c = 0; c < 4; c++) {
            f32x4 acc = {0.f, 0.f, 0.f, 0.f};
            acc = mfma16(kv0[c], aq0, acc);
            acc = mfma16(kv1[c], aq1, acc);
            int kbase = n0 + c * 16 + g * 4;
            int4 dd = dd4[c];
            float e0 = __expf(acc[0]) * qdr_lds[l16][dd.x < 9 ? dd.x : 9];
            float e1 = __expf(acc[1]) * qdr_lds[l16][dd.y < 9 ? dd.y : 9];
            float e2 = __expf(acc[2]) * qdr_lds[l16][dd.z < 9 ? dd.z : 9];
            float e3 = __expf(acc[3]) * qdr_lds[l16][dd.w < 9 ? dd.w : 9];
            rs += (e0 + e1) + (e2 + e3);
            unsigned u = __builtin_amdgcn_cvt_pk_fp8_f32(e0, e1, 0, false);
            u = (unsigned)__builtin_amdgcn_cvt_pk_fp8_f32(e2, e3, (int)u, true);
            *(unsigned*)&P[l16][kbase] = u;
        }
        #pragma unroll
        for (int c = 0; c < 4; c++) dd4[c] = ddn[c];
    }
    rs += __shfl_xor(rs, 16);
    rs += __shfl_xor(rs, 32);
    if (lane < 16) comb[ph][l16] = rs;
    __syncthreads();
    if (t < 16) {
        float s = 0.f;
        #pragma unroll
        for (int w = 0; w < 8; w++) s += comb[w][t];
        inv_lds[t] = 1.0f / s;
    }
    __syncthreads();

    // ---------------- pass 2: fp8 PV MFMA + coalesced a_out store -------------
    const unsigned char* Vb0 = vtb8 + ((size_t)bh * 64 + l16) * NE;
    f32x4 accp[4];
    {
        f32x4 z4 = {0.f, 0.f, 0.f, 0.f};
        #pragma unroll
        for (int c = 0; c < 4; c++) accp[c] = z4;
    }
    #pragma unroll 1
    for (int j = 0; j < 4; j++) {
        int n0 = (ph + 8 * j) * 64;
        long long vb0[4], vb1[4];
        #pragma unroll
        for (int c = 0; c < 4; c++) {
            const unsigned char* Vb = Vb0 + (size_t)c * 16 * NE + n0 + g * 8;
            vb0[c] = *(const long long*)(Vb);
            vb1[c] = *(const long long*)(Vb + 32);
        }
        long long pa0 = *(const long long*)&P[l16][n0 + g * 8];
        long long pa1 = *(const long long*)&P[l16][n0 + 32 + g * 8];
        #pragma unroll
        for (int c = 0; c < 4; c++) {
            accp[c] = mfma8(pa0, vb0[c], accp[c]);
            accp[c] = mfma8(pa1, vb1[c], accp[c]);
        }
        #pragma unroll
        for (int r4 = 0; r4 < 4; r4++) {
            int row = r4 * 4 + g;
            unsigned u = *(const unsigned*)&P[row][n0 + l16 * 4];
            float iv = inv_lds[row];
            f32x4 o;
            o[0] = __builtin_amdgcn_cvt_f32_fp8((int)u, 0) * iv;
            o[1] = __builtin_amdgcn_cvt_f32_fp8((int)u, 1) * iv;
            o[2] = __builtin_amdgcn_cvt_f32_fp8((int)u, 2) * iv;
            o[3] = __builtin_amdgcn_cvt_f32_fp8((int)u, 3) * iv;
            *(f32x4*)&a_out[((size_t)bh * NE + m0 + row) * NE + n0 + l16 * 4] = o;
        }
    }

    // ---------------- combine PV partials across 8 waves (alias P) ------------
    __syncthreads();
    float (*pvcomb)[16][64] = (float (*)[16][64])&P[0][0];  // 28.7 KB <= 33 KB
    if (ph > 0) {
        #pragma unroll
        for (int c = 0; c < 4; c++)
            #pragma unroll
            for (int r = 0; r < 4; r++)
                pvcomb[ph - 1][g * 4 + r][c * 16 + l16] = accp[c][r];
    }
    __syncthreads();
    if (ph == 0) {
        #pragma unroll
        for (int c = 0; c < 4; c++) {
            #pragma unroll
            for (int r = 0; r < 4; r++) {
                float v = accp[c][r];
                #pragma unroll
                for (int w = 0; w < 7; w++) v += pvcomb[w][g * 4 + r][c * 16 + l16];
                v *= inv_lds[g * 4 + r];
                oatb[(size_t)(b * NE + m0 + g * 4 + r) * 256 + h * 64 + c * 16 + l16] = f2b(v);
            }
        }
    }
}

// ---------------- fc GEMM + residual from x + transposed store ----------------
__global__ __launch_bounds__(256) void k_gemm_fc(const short* __restrict__ A,
        const short* __restrict__ W, const float* __restrict__ x,
        float* __restrict__ xout) {
    int t = threadIdx.x;
    int wv_ = t >> 6, lane = t & 63;
    int l16 = lane & 15, g = lane >> 4, lk = g * 8;
    int m0 = blockIdx.x * 64, n0 = blockIdx.y * 64;
    int mw = m0 + wv_ * 16;
    const short* Ab = A + (size_t)(mw + l16) * 256 + lk;
    const short* Wb = W + (size_t)(n0 + l16) * 256 + lk;
    f32x4 acc[4];
    f32x4 z4 = {0.f, 0.f, 0.f, 0.f};
    #pragma unroll
    for (int c = 0; c < 4; c++) acc[c] = z4;
    #pragma unroll
    for (int kk = 0; kk < 8; kk++) {
        bf16x8 av = *(const bf16x8*)(Ab + kk * 32);
        #pragma unroll
        for (int c = 0; c < 4; c++) {
            bf16x8 bv = *(const bf16x8*)(Wb + (size_t)c * 16 * 256 + kk * 32);
            acc[c] = mfma16(av, bv, acc[c]);
        }
    }
    __shared__ float tl[64][68];
    #pragma unroll
    for (int c = 0; c < 4; c++)
        #pragma unroll
        for (int r = 0; r < 4; r++)
            tl[c * 16 + l16][wv_ * 16 + g * 4 + r] = acc[c][r];
    __syncthreads();
    int b = m0 >> 11, e0 = m0 & (NE - 1);
    int dl = t >> 2, ec = (t & 3) * 16;
    #pragma unroll
    for (int i = 0; i < 4; i++) {
        size_t idx = ((size_t)b * ND + n0 + dl) * NE + e0 + ec + i * 4;
        f32x4 xv = *(const f32x4*)&x[idx];
        f32x4 v = *(f32x4*)&tl[dl][ec + i * 4];
        v[0] += xv[0]; v[1] += xv[1]; v[2] += xv[2]; v[3] += xv[3];
        *(f32x4*)&xout[idx] = v;
    }
}

extern "C" void kernel_launch(void* const* d_in, const int* in_sizes, int n_in,
                              void* d_out, int out_size, void* d_ws, size_t ws_size,
                              hipStream_t stream) {
    const float* x    = (const float*)d_in[0];
    const int*   dist = (const int*)d_in[1];
    const float* w_qs = (const float*)d_in[2];
    const float* w_ks = (const float*)d_in[3];
    const float* w_vs = (const float*)d_in[4];
    const float* w_fc = (const float*)d_in[5];
    const float* w_rpr= (const float*)d_in[6];
    const float* ln_g = (const float*)d_in[7];
    const float* ln_b = (const float*)d_in[8];

    char* ws = (char*)d_ws;
    short* sbf  = (short*)(ws);                    // 2 MB
    short* qnb  = (short*)(ws + (2u  << 20));      // 2 MB
    short* qbf  = (short*)(ws + (4u  << 20));      // 2 MB
    short* kbf  = (short*)(ws + (6u  << 20));      // 2 MB
    unsigned char* vtb8 = (unsigned char*)(ws + (8u << 20));  // 1 MB
    short* oatb = (short*)(ws + (10u << 20));      // 2 MB
    float* qdrT = (float*)(ws + (12u << 20));      // 640 KB
    short* wqsb = (short*)(ws + (13u << 20));
    short* wksb = (short*)(ws + (13u << 20) + 131072);
    short* wvsb = (short*)(ws + (13u << 20) + 262144);
    short* wfcb = (short*)(ws + (13u << 20) + 393216);

    float* xout  = (float*)d_out;
    float* a_out = xout + (size_t)NB * ND * NE;

    k_cvt_all<<<dim3(256), dim3(256), 0, stream>>>(w_qs, w_ks, w_vs, w_fc,
                                                   wqsb, wksb, wvsb, wfcb);
    k_prep<<<dim3(NE / 32, NB), dim3(256), 0, stream>>>(x, ln_g, ln_b, sbf, qnb);
    k_gemm_qkv<<<dim3(64, 4, 3), dim3(256), 0, stream>>>(qnb, sbf, wqsb, wksb, wvsb,
                                                         w_rpr, qbf, kbf, vtb8, qdrT);
    k_attn<<<dim3(NE / 16, NB * NH), dim3(512), 0, stream>>>(qbf, kbf, dist, qdrT,
                                                             vtb8, a_out, oatb);
    k_gemm_fc<<<dim3(64, 4), dim3(256), 0, stream>>>(oatb, wfcb, x, xout);
}